// Round 1
// baseline (2418.655 us; speedup 1.0000x reference)
//
#include <hip/hip_runtime.h>
#include <hip/hip_bf16.h>

#define FEAT 128

// ---------------------------------------------------------------- degrees
__global__ __launch_bounds__(256)
void deg_kernel(const int* __restrict__ src, const int* __restrict__ dst,
                float* __restrict__ degOut, float* __restrict__ degIn, int E)
{
    int e = blockIdx.x * 256 + threadIdx.x;
    if (e < E) {
        unsafeAtomicAdd(&degOut[src[e]], 1.0f);
        unsafeAtomicAdd(&degIn[dst[e]], 1.0f);
    }
}

__global__ __launch_bounds__(256)
void norm_kernel(float* __restrict__ degOut, float* __restrict__ degIn, int N)
{
    int i = blockIdx.x * 256 + threadIdx.x;
    if (i < N) {
        float a = degOut[i];
        degOut[i] = (a > 0.5f) ? rsqrtf(a) : 0.0f;
        float b = degIn[i];
        degIn[i] = (b > 0.5f) ? rsqrtf(b) : 0.0f;
    }
}

// ---------------------------------------------------------------- GEMM
// C[row][:] = postN[row] * (Atrans(row,:) @ W),  A:[M,128], W:[128,128]
// Atrans = PRE ? relu(A*preN[row] + bias[k]) : A
// Block: 128 threads (2 waves), tile 64 rows x 128 cols, per-thread 8x8.
template<bool PRE>
__global__ __launch_bounds__(128)
void gemm_kernel(const float* __restrict__ A, const float* __restrict__ W,
                 const float* __restrict__ preN, const float* __restrict__ bias,
                 const float* __restrict__ postN, float* __restrict__ C, int M)
{
    __shared__ float Ast[16][68];    // [k][row], transposed for broadcast reads
    __shared__ float Bs[16][132];    // [k][col]

    const int tid = threadIdx.x;
    const int wv  = tid >> 6;        // 0..1 -> column half
    const int ln  = tid & 63;
    const int ra  = ln >> 3;         // 0..7 -> row octet
    const int ca  = ln & 7;          // 0..7 -> col octet within half
    const int row0 = blockIdx.x << 6;

    float acc[8][8];
#pragma unroll
    for (int i = 0; i < 8; ++i)
#pragma unroll
        for (int j = 0; j < 8; ++j) acc[i][j] = 0.0f;

    for (int k0 = 0; k0 < FEAT; k0 += 16) {
        // stage A (64 rows x 16 k): 2 float4 per thread, transposed store
#pragma unroll
        for (int t = 0; t < 2; ++t) {
            int fid = tid + (t << 7);        // 0..255
            int r   = fid >> 2;              // 0..63
            int kq  = (fid & 3) << 2;        // 0,4,8,12
            int grow = row0 + r;
            float4 v = make_float4(0.f, 0.f, 0.f, 0.f);
            if (grow < M) {
                v = *(const float4*)(A + (size_t)grow * FEAT + k0 + kq);
                if (PRE) {
                    float ni = preN[grow];
                    const float4 b = *(const float4*)(bias + k0 + kq);
                    v.x = fmaxf(fmaf(v.x, ni, b.x), 0.0f);
                    v.y = fmaxf(fmaf(v.y, ni, b.y), 0.0f);
                    v.z = fmaxf(fmaf(v.z, ni, b.z), 0.0f);
                    v.w = fmaxf(fmaf(v.w, ni, b.w), 0.0f);
                }
            }
            Ast[kq + 0][r] = v.x;
            Ast[kq + 1][r] = v.y;
            Ast[kq + 2][r] = v.z;
            Ast[kq + 3][r] = v.w;
        }
        // stage B (16 k x 128 cols): 4 float4 per thread
#pragma unroll
        for (int i = 0; i < 4; ++i) {
            int fid = tid + (i << 7);        // 0..511
            int k   = fid >> 5;              // 0..15
            int c   = (fid & 31) << 2;       // 0..124
            *(float4*)&Bs[k][c] = *(const float4*)(W + (size_t)(k0 + k) * FEAT + c);
        }
        __syncthreads();

#pragma unroll
        for (int k = 0; k < 16; ++k) {
            const float4 a0 = *(const float4*)&Ast[k][ra * 8];
            const float4 a1 = *(const float4*)&Ast[k][ra * 8 + 4];
            const float4 b0 = *(const float4*)&Bs[k][wv * 64 + ca * 8];
            const float4 b1 = *(const float4*)&Bs[k][wv * 64 + ca * 8 + 4];
            const float av[8] = {a0.x, a0.y, a0.z, a0.w, a1.x, a1.y, a1.z, a1.w};
            const float bv[8] = {b0.x, b0.y, b0.z, b0.w, b1.x, b1.y, b1.z, b1.w};
#pragma unroll
            for (int i = 0; i < 8; ++i)
#pragma unroll
                for (int j = 0; j < 8; ++j)
                    acc[i][j] = fmaf(av[i], bv[j], acc[i][j]);
        }
        __syncthreads();
    }

    // epilogue: scale rows by postN, store
#pragma unroll
    for (int i = 0; i < 8; ++i) {
        int grow = row0 + ra * 8 + i;
        if (grow < M) {
            float s = postN[grow];
            float4 o0 = make_float4(acc[i][0] * s, acc[i][1] * s, acc[i][2] * s, acc[i][3] * s);
            float4 o1 = make_float4(acc[i][4] * s, acc[i][5] * s, acc[i][6] * s, acc[i][7] * s);
            float* p = C + (size_t)grow * FEAT + wv * 64 + ca * 8;
            *(float4*)(p)     = o0;
            *(float4*)(p + 4) = o1;
        }
    }
}

// ---------------------------------------------------------------- scatter
// agg[dst[e]][:] += hW[src[e]][:]   (32 threads per edge, float4 each)
__global__ __launch_bounds__(256)
void scatter_kernel(const float* __restrict__ hW, const int* __restrict__ src,
                    const int* __restrict__ dst, float* __restrict__ agg, int E)
{
    int idx = blockIdx.x * 256 + threadIdx.x;
    int e = idx >> 5;
    if (e >= E) return;
    int f = (idx & 31) << 2;
    const float4 v = *(const float4*)(hW + (size_t)src[e] * FEAT + f);
    float* p = agg + (size_t)dst[e] * FEAT + f;
    unsafeAtomicAdd(p + 0, v.x);
    unsafeAtomicAdd(p + 1, v.y);
    unsafeAtomicAdd(p + 2, v.z);
    unsafeAtomicAdd(p + 3, v.w);
}

// ---------------------------------------------------------------- column mean (fused relu(agg*normIn + b2))
__global__ __launch_bounds__(256)
void colreduce_kernel(const float* __restrict__ agg, const float* __restrict__ normIn,
                      const float* __restrict__ bias, float* __restrict__ colsum, int N)
{
    const int c  = threadIdx.x & 127;
    const int rg = threadIdx.x >> 7;         // 0..1
    const int r0 = blockIdx.x * 256;
    const int rEnd = min(r0 + 256, N);
    float b = bias[c];
    float acc = 0.0f;
    for (int r = r0 + rg; r < rEnd; r += 2) {
        float ni = normIn[r];
        float v = fmaf(agg[(size_t)r * FEAT + c], ni, b);
        acc += fmaxf(v, 0.0f);
    }
    __shared__ float sh[256];
    sh[threadIdx.x] = acc;
    __syncthreads();
    if (rg == 0) unsafeAtomicAdd(&colsum[c], sh[c] + sh[128 + c]);
}

// ---------------------------------------------------------------- final readout
__global__ __launch_bounds__(128)
void final_kernel(const float* __restrict__ colsum, const float* __restrict__ Wr,
                  const float* __restrict__ br, float* __restrict__ out, float invN)
{
    __shared__ float s0[128], s1[128];
    int j = threadIdx.x;
    float hg = colsum[j] * invN;
    s0[j] = hg * Wr[2 * j + 0];
    s1[j] = hg * Wr[2 * j + 1];
    __syncthreads();
    for (int off = 64; off > 0; off >>= 1) {
        if (j < off) { s0[j] += s0[j + off]; s1[j] += s1[j + off]; }
        __syncthreads();
    }
    if (j == 0) {
        out[0] = s0[0] + br[0];
        out[1] = s1[0] + br[1];
    }
}

// ---------------------------------------------------------------- launch
extern "C" void kernel_launch(void* const* d_in, const int* in_sizes, int n_in,
                              void* d_out, int out_size, void* d_ws, size_t ws_size,
                              hipStream_t stream)
{
    const float* x   = (const float*)d_in[0];
    const int*   src = (const int*)d_in[1];
    const int*   dst = (const int*)d_in[2];
    const float* W1  = (const float*)d_in[3];
    const float* b1  = (const float*)d_in[4];
    const float* W2  = (const float*)d_in[5];
    const float* b2  = (const float*)d_in[6];
    const float* Wr  = (const float*)d_in[7];
    const float* br  = (const float*)d_in[8];
    float* out = (float*)d_out;

    const int N = in_sizes[0] / FEAT;    // 50000
    const int E = in_sizes[1];           // 640000

    // workspace layout (floats)
    const int NP = ((N + 63) / 64) * 64;           // 50048
    float* ws      = (float*)d_ws;
    float* normOut = ws;                            // NP
    float* normIn  = ws + NP;                       // NP
    float* colsum  = ws + 2 * NP;                   // 128 (+pad to 256)
    float* bufA    = ws + 2 * NP + 256;             // N*FEAT
    float* bufB    = bufA + (size_t)N * FEAT;       // N*FEAT

    // zero degrees + colsum, zero layer-1 agg buffer
    hipMemsetAsync(ws, 0, (size_t)(2 * NP + 256) * sizeof(float), stream);
    hipMemsetAsync(bufB, 0, (size_t)N * FEAT * sizeof(float), stream);

    deg_kernel<<<(E + 255) / 256, 256, 0, stream>>>(src, dst, normOut, normIn, E);
    norm_kernel<<<(N + 255) / 256, 256, 0, stream>>>(normOut, normIn, N);

    const int gemmBlocks = (N + 63) / 64;
    const int scatBlocks = (E * 32 + 255) / 256;

    // layer 1: bufA = (x * normOut) @ W1 ; bufB = scatter(bufA)
    gemm_kernel<false><<<gemmBlocks, 128, 0, stream>>>(x, W1, nullptr, nullptr, normOut, bufA, N);
    scatter_kernel<<<scatBlocks, 256, 0, stream>>>(bufA, src, dst, bufB, E);

    // layer 2: bufA = (relu(bufB*normIn + b1) * normOut) @ W2 ; bufB = scatter(bufA)
    gemm_kernel<true><<<gemmBlocks, 128, 0, stream>>>(bufB, W2, normIn, b1, normOut, bufA, N);
    hipMemsetAsync(bufB, 0, (size_t)N * FEAT * sizeof(float), stream);
    scatter_kernel<<<scatBlocks, 256, 0, stream>>>(bufA, src, dst, bufB, E);

    // readout: colsum = sum_rows relu(bufB*normIn + b2); out = colsum/N @ Wr + br
    colreduce_kernel<<<(N + 255) / 256, 256, 0, stream>>>(bufB, normIn, b2, colsum, N);
    final_kernel<<<1, 128, 0, stream>>>(colsum, Wr, br, out, 1.0f / (float)N);
}

// Round 2
// 385.907 us; speedup vs baseline: 6.2675x; 6.2675x over previous
//
#include <hip/hip_runtime.h>
#include <hip/hip_bf16.h>

#define FEAT 128

// ---------------------------------------------------------------- degree histogram (int)
__global__ __launch_bounds__(256)
void deg_kernel(const int* __restrict__ src, const int* __restrict__ dst,
                int* __restrict__ cntOut, int* __restrict__ cntIn, int E)
{
    int e = blockIdx.x * 256 + threadIdx.x;
    if (e < E) {
        atomicAdd(&cntOut[src[e]], 1);
        atomicAdd(&cntIn[dst[e]], 1);
    }
}

__global__ __launch_bounds__(256)
void norm_kernel(const int* __restrict__ cntOut, const int* __restrict__ cntIn,
                 float* __restrict__ normOut, float* __restrict__ normIn, int N)
{
    int i = blockIdx.x * 256 + threadIdx.x;
    if (i < N) {
        int a = cntOut[i];
        normOut[i] = (a > 0) ? rsqrtf((float)a) : 0.0f;
        int b = cntIn[i];
        normIn[i] = (b > 0) ? rsqrtf((float)b) : 0.0f;
    }
}

// ---------------------------------------------------------------- scan (3 kernels, N<=65536)
__global__ __launch_bounds__(256)
void scan1_kernel(const int* __restrict__ cnt, int* __restrict__ blockSums, int N)
{
    __shared__ int sh[256];
    int i = blockIdx.x * 256 + threadIdx.x;
    sh[threadIdx.x] = (i < N) ? cnt[i] : 0;
    __syncthreads();
    for (int off = 128; off > 0; off >>= 1) {
        if (threadIdx.x < off) sh[threadIdx.x] += sh[threadIdx.x + off];
        __syncthreads();
    }
    if (threadIdx.x == 0) blockSums[blockIdx.x] = sh[0];
}

__global__ __launch_bounds__(256)
void scan2_kernel(int* __restrict__ blockSums, int* __restrict__ totalOut, int nb)
{
    __shared__ int sh[256];
    int t = threadIdx.x;
    int v = (t < nb) ? blockSums[t] : 0;
    sh[t] = v;
    __syncthreads();
    for (int off = 1; off < 256; off <<= 1) {
        int u = (t >= off) ? sh[t - off] : 0;
        __syncthreads();
        sh[t] += u;
        __syncthreads();
    }
    if (t < nb) blockSums[t] = sh[t] - v;        // exclusive
    if (t == 255) *totalOut = sh[255];
}

__global__ __launch_bounds__(256)
void scan3_kernel(const int* __restrict__ cnt, const int* __restrict__ blockSums,
                  int* __restrict__ rowStart, int* __restrict__ cursor, int N)
{
    __shared__ int sh[256];
    int t = threadIdx.x;
    int i = blockIdx.x * 256 + t;
    int v = (i < N) ? cnt[i] : 0;
    sh[t] = v;
    __syncthreads();
    for (int off = 1; off < 256; off <<= 1) {
        int u = (t >= off) ? sh[t - off] : 0;
        __syncthreads();
        sh[t] += u;
        __syncthreads();
    }
    if (i < N) {
        int rs = blockSums[blockIdx.x] + sh[t] - v;   // exclusive prefix
        rowStart[i] = rs;
        cursor[i]   = rs;
    }
}

// ---------------------------------------------------------------- CSR fill
__global__ __launch_bounds__(256)
void fill_kernel(const int* __restrict__ src, const int* __restrict__ dst,
                 int* __restrict__ cursor, int* __restrict__ csrSrc, int E)
{
    int e = blockIdx.x * 256 + threadIdx.x;
    if (e < E) {
        int pos = atomicAdd(&cursor[dst[e]], 1);
        csrSrc[pos] = src[e];
    }
}

// ---------------------------------------------------------------- gather aggregate
// out[n][:] = sum_{j in in-edges(n)} hW[csrSrc[j]][:]
// one half-wave (32 lanes x float4) per node
__global__ __launch_bounds__(256)
void gather_kernel(const float* __restrict__ hW, const int* __restrict__ rowStart,
                   const int* __restrict__ csrSrc, float* __restrict__ out, int N)
{
    const int hw   = threadIdx.x >> 5;           // 0..7
    const int lane = threadIdx.x & 31;
    const int node = blockIdx.x * 8 + hw;
    if (node >= N) return;
    const int s = rowStart[node];
    const int e = rowStart[node + 1];
    float4 acc = make_float4(0.f, 0.f, 0.f, 0.f);
    for (int base = s; base < e; base += 32) {
        const int m = min(32, e - base);
        int idx = (base + lane < e) ? csrSrc[base + lane] : 0;
#pragma unroll 4
        for (int j = 0; j < m; ++j) {
            int srcn = __shfl(idx, j, 32);
            const float4 v = *(const float4*)(hW + (size_t)srcn * FEAT + lane * 4);
            acc.x += v.x; acc.y += v.y; acc.z += v.z; acc.w += v.w;
        }
    }
    *(float4*)(out + (size_t)node * FEAT + lane * 4) = acc;
}

// ---------------------------------------------------------------- GEMM
// C[row][:] = postN[row] * (Atrans(row,:) @ W),  A:[M,128], W:[128,128]
// Atrans = PRE ? relu(A*preN[row] + bias[k]) : A
// Block: 128 threads (2 waves), tile 64 rows x 128 cols, per-thread 8x8.
template<bool PRE>
__global__ __launch_bounds__(128)
void gemm_kernel(const float* __restrict__ A, const float* __restrict__ W,
                 const float* __restrict__ preN, const float* __restrict__ bias,
                 const float* __restrict__ postN, float* __restrict__ C, int M)
{
    __shared__ float Ast[16][68];    // [k][row], transposed for broadcast reads
    __shared__ float Bs[16][132];    // [k][col]

    const int tid = threadIdx.x;
    const int wv  = tid >> 6;        // 0..1 -> column half
    const int ln  = tid & 63;
    const int ra  = ln >> 3;         // 0..7 -> row octet
    const int ca  = ln & 7;          // 0..7 -> col octet within half
    const int row0 = blockIdx.x << 6;

    float acc[8][8];
#pragma unroll
    for (int i = 0; i < 8; ++i)
#pragma unroll
        for (int j = 0; j < 8; ++j) acc[i][j] = 0.0f;

    for (int k0 = 0; k0 < FEAT; k0 += 16) {
#pragma unroll
        for (int t = 0; t < 2; ++t) {
            int fid = tid + (t << 7);        // 0..255
            int r   = fid >> 2;              // 0..63
            int kq  = (fid & 3) << 2;        // 0,4,8,12
            int grow = row0 + r;
            float4 v = make_float4(0.f, 0.f, 0.f, 0.f);
            if (grow < M) {
                v = *(const float4*)(A + (size_t)grow * FEAT + k0 + kq);
                if (PRE) {
                    float ni = preN[grow];
                    const float4 b = *(const float4*)(bias + k0 + kq);
                    v.x = fmaxf(fmaf(v.x, ni, b.x), 0.0f);
                    v.y = fmaxf(fmaf(v.y, ni, b.y), 0.0f);
                    v.z = fmaxf(fmaf(v.z, ni, b.z), 0.0f);
                    v.w = fmaxf(fmaf(v.w, ni, b.w), 0.0f);
                }
            }
            Ast[kq + 0][r] = v.x;
            Ast[kq + 1][r] = v.y;
            Ast[kq + 2][r] = v.z;
            Ast[kq + 3][r] = v.w;
        }
#pragma unroll
        for (int i = 0; i < 4; ++i) {
            int fid = tid + (i << 7);        // 0..511
            int k   = fid >> 5;              // 0..15
            int c   = (fid & 31) << 2;       // 0..124
            *(float4*)&Bs[k][c] = *(const float4*)(W + (size_t)(k0 + k) * FEAT + c);
        }
        __syncthreads();

#pragma unroll
        for (int k = 0; k < 16; ++k) {
            const float4 a0 = *(const float4*)&Ast[k][ra * 8];
            const float4 a1 = *(const float4*)&Ast[k][ra * 8 + 4];
            const float4 b0 = *(const float4*)&Bs[k][wv * 64 + ca * 8];
            const float4 b1 = *(const float4*)&Bs[k][wv * 64 + ca * 8 + 4];
            const float av[8] = {a0.x, a0.y, a0.z, a0.w, a1.x, a1.y, a1.z, a1.w};
            const float bv[8] = {b0.x, b0.y, b0.z, b0.w, b1.x, b1.y, b1.z, b1.w};
#pragma unroll
            for (int i = 0; i < 8; ++i)
#pragma unroll
                for (int j = 0; j < 8; ++j)
                    acc[i][j] = fmaf(av[i], bv[j], acc[i][j]);
        }
        __syncthreads();
    }

#pragma unroll
    for (int i = 0; i < 8; ++i) {
        int grow = row0 + ra * 8 + i;
        if (grow < M) {
            float s = postN[grow];
            float4 o0 = make_float4(acc[i][0] * s, acc[i][1] * s, acc[i][2] * s, acc[i][3] * s);
            float4 o1 = make_float4(acc[i][4] * s, acc[i][5] * s, acc[i][6] * s, acc[i][7] * s);
            float* p = C + (size_t)grow * FEAT + wv * 64 + ca * 8;
            *(float4*)(p)     = o0;
            *(float4*)(p + 4) = o1;
        }
    }
}

// ---------------------------------------------------------------- column mean (fused relu(agg*normIn + b2))
__global__ __launch_bounds__(256)
void colreduce_kernel(const float* __restrict__ agg, const float* __restrict__ normIn,
                      const float* __restrict__ bias, float* __restrict__ colsum, int N)
{
    const int c  = threadIdx.x & 127;
    const int rg = threadIdx.x >> 7;         // 0..1
    const int r0 = blockIdx.x * 256;
    const int rEnd = min(r0 + 256, N);
    float b = bias[c];
    float acc = 0.0f;
    for (int r = r0 + rg; r < rEnd; r += 2) {
        float ni = normIn[r];
        float v = fmaf(agg[(size_t)r * FEAT + c], ni, b);
        acc += fmaxf(v, 0.0f);
    }
    __shared__ float sh[256];
    sh[threadIdx.x] = acc;
    __syncthreads();
    if (rg == 0) unsafeAtomicAdd(&colsum[c], sh[c] + sh[128 + c]);
}

// ---------------------------------------------------------------- final readout
__global__ __launch_bounds__(128)
void final_kernel(const float* __restrict__ colsum, const float* __restrict__ Wr,
                  const float* __restrict__ br, float* __restrict__ out, float invN)
{
    __shared__ float s0[128], s1[128];
    int j = threadIdx.x;
    float hg = colsum[j] * invN;
    s0[j] = hg * Wr[2 * j + 0];
    s1[j] = hg * Wr[2 * j + 1];
    __syncthreads();
    for (int off = 64; off > 0; off >>= 1) {
        if (j < off) { s0[j] += s0[j + off]; s1[j] += s1[j + off]; }
        __syncthreads();
    }
    if (j == 0) {
        out[0] = s0[0] + br[0];
        out[1] = s1[0] + br[1];
    }
}

// ---------------------------------------------------------------- launch
extern "C" void kernel_launch(void* const* d_in, const int* in_sizes, int n_in,
                              void* d_out, int out_size, void* d_ws, size_t ws_size,
                              hipStream_t stream)
{
    const float* x   = (const float*)d_in[0];
    const int*   src = (const int*)d_in[1];
    const int*   dst = (const int*)d_in[2];
    const float* W1  = (const float*)d_in[3];
    const float* b1  = (const float*)d_in[4];
    const float* W2  = (const float*)d_in[5];
    const float* b2  = (const float*)d_in[6];
    const float* Wr  = (const float*)d_in[7];
    const float* br  = (const float*)d_in[8];
    float* out = (float*)d_out;

    const int N = in_sizes[0] / FEAT;    // 50000
    const int E = in_sizes[1];           // 640000
    const int NP = ((N + 255) / 256) * 256;   // padded
    const int NB = (N + 255) / 256;           // scan blocks (<=256 required)

    // workspace layout
    char* p = (char*)d_ws;
    int*   cntOut   = (int*)p;            p += (size_t)NP * 4;   // later reused as cursor
    int*   cntIn    = (int*)p;            p += (size_t)NP * 4;
    float* colsum   = (float*)p;          p += 256 * 4;
    int*   blockSums= (int*)p;            p += 256 * 4;
    float* normOut  = (float*)p;          p += (size_t)NP * 4;
    float* normIn   = (float*)p;          p += (size_t)NP * 4;
    int*   rowStart = (int*)p;            p += (size_t)(NP + 64) * 4;
    int*   csrSrc   = (int*)p;            p += (size_t)E * 4;
    float* bufA     = (float*)p;          p += (size_t)N * FEAT * 4;
    float* bufB     = (float*)p;

    int* cursor = cntOut;   // cntOut dead after norm_kernel

    // zero cnt arrays + colsum + blockSums (contiguous at front)
    hipMemsetAsync(d_ws, 0, (size_t)(2 * NP + 512) * 4, stream);

    // degrees + norms
    deg_kernel<<<(E + 255) / 256, 256, 0, stream>>>(src, dst, cntOut, cntIn, E);
    norm_kernel<<<NB, 256, 0, stream>>>(cntOut, cntIn, normOut, normIn, N);

    // CSR build over dst
    scan1_kernel<<<NB, 256, 0, stream>>>(cntIn, blockSums, N);
    scan2_kernel<<<1, 256, 0, stream>>>(blockSums, rowStart + N, NB);
    scan3_kernel<<<NB, 256, 0, stream>>>(cntIn, blockSums, rowStart, cursor, N);
    fill_kernel<<<(E + 255) / 256, 256, 0, stream>>>(src, dst, cursor, csrSrc, E);

    const int gemmBlocks = (N + 63) / 64;
    const int gathBlocks = (N + 7) / 8;

    // layer 1: bufA = (x * normOut) @ W1 ; bufB = gather(bufA)
    gemm_kernel<false><<<gemmBlocks, 128, 0, stream>>>(x, W1, nullptr, nullptr, normOut, bufA, N);
    gather_kernel<<<gathBlocks, 256, 0, stream>>>(bufA, rowStart, csrSrc, bufB, N);

    // layer 2: bufA = (relu(bufB*normIn + b1) * normOut) @ W2 ; bufB = gather(bufA)
    gemm_kernel<true><<<gemmBlocks, 128, 0, stream>>>(bufB, W2, normIn, b1, normOut, bufA, N);
    gather_kernel<<<gathBlocks, 256, 0, stream>>>(bufA, rowStart, csrSrc, bufB, N);

    // readout: colsum = sum_rows relu(bufB*normIn + b2); out = colsum/N @ Wr + br
    colreduce_kernel<<<NB, 256, 0, stream>>>(bufB, normIn, b2, colsum, N);
    final_kernel<<<1, 128, 0, stream>>>(colsum, Wr, br, out, 1.0f / (float)N);
}

// Round 3
// 318.263 us; speedup vs baseline: 7.5995x; 1.2125x over previous
//
#include <hip/hip_runtime.h>
#include <hip/hip_bf16.h>

#define FEAT 128

typedef __attribute__((ext_vector_type(8))) short short8;
typedef __attribute__((ext_vector_type(4))) short short4v;
typedef __attribute__((ext_vector_type(4))) float f32x4;

__device__ __forceinline__ ushort f2bf(float f) {
    union { float f; unsigned u; } v; v.f = f;
    unsigned u = v.u;
    unsigned r = 0x7fffu + ((u >> 16) & 1u);
    return (ushort)((u + r) >> 16);
}
__device__ __forceinline__ float bf2f(short s) {
    union { unsigned u; float f; } v;
    v.u = ((unsigned)(ushort)s) << 16;
    return v.f;
}

// ---------------------------------------------------------------- degree histogram
__global__ __launch_bounds__(256)
void deg_kernel(const int* __restrict__ src, const int* __restrict__ dst,
                int* __restrict__ cntOut, int* __restrict__ cntIn, int E)
{
    int e = blockIdx.x * 256 + threadIdx.x;
    if (e < E) {
        atomicAdd(&cntOut[src[e]], 1);
        atomicAdd(&cntIn[dst[e]], 1);
    }
}

// ---------------------------------------------------------------- scan (3 kernels)
__global__ __launch_bounds__(256)
void scan1_kernel(const int* __restrict__ cnt, int* __restrict__ blockSums, int N)
{
    __shared__ int sh[256];
    int i = blockIdx.x * 256 + threadIdx.x;
    sh[threadIdx.x] = (i < N) ? cnt[i] : 0;
    __syncthreads();
    for (int off = 128; off > 0; off >>= 1) {
        if (threadIdx.x < off) sh[threadIdx.x] += sh[threadIdx.x + off];
        __syncthreads();
    }
    if (threadIdx.x == 0) blockSums[blockIdx.x] = sh[0];
}

__global__ __launch_bounds__(256)
void scan2_kernel(int* __restrict__ blockSums, int* __restrict__ totalOut, int nb)
{
    __shared__ int sh[256];
    int t = threadIdx.x;
    int v = (t < nb) ? blockSums[t] : 0;
    sh[t] = v;
    __syncthreads();
    for (int off = 1; off < 256; off <<= 1) {
        int u = (t >= off) ? sh[t - off] : 0;
        __syncthreads();
        sh[t] += u;
        __syncthreads();
    }
    if (t < nb) blockSums[t] = sh[t] - v;
    if (t == 255) *totalOut = sh[255];
}

// scan3 + norm computation fused
__global__ __launch_bounds__(256)
void scan3_kernel(const int* __restrict__ cntIn, const int* __restrict__ cntOut,
                  const int* __restrict__ blockSums,
                  int* __restrict__ rowStart, int* __restrict__ cursor,
                  float* __restrict__ normOut, float* __restrict__ normIn, int N)
{
    __shared__ int sh[256];
    int t = threadIdx.x;
    int i = blockIdx.x * 256 + t;
    int v = (i < N) ? cntIn[i] : 0;
    sh[t] = v;
    __syncthreads();
    for (int off = 1; off < 256; off <<= 1) {
        int u = (t >= off) ? sh[t - off] : 0;
        __syncthreads();
        sh[t] += u;
        __syncthreads();
    }
    if (i < N) {
        int rs = blockSums[blockIdx.x] + sh[t] - v;
        rowStart[i] = rs;
        cursor[i]   = rs;
        normIn[i]  = (v > 0) ? rsqrtf((float)v) : 0.0f;
        int a = cntOut[i];
        normOut[i] = (a > 0) ? rsqrtf((float)a) : 0.0f;
    }
}

// ---------------------------------------------------------------- CSR fill
__global__ __launch_bounds__(256)
void fill_kernel(const int* __restrict__ src, const int* __restrict__ dst,
                 int* __restrict__ cursor, int* __restrict__ csrSrc, int E)
{
    int e = blockIdx.x * 256 + threadIdx.x;
    if (e < E) {
        int pos = atomicAdd(&cursor[dst[e]], 1);
        csrSrc[pos] = src[e];
    }
}

// ---------------------------------------------------------------- fp32 -> bf16 convert
__global__ __launch_bounds__(256)
void convert_kernel(const float* __restrict__ x, ushort* __restrict__ xb, int total4)
{
    int i = blockIdx.x * 256 + threadIdx.x;
    if (i < total4) {
        float4 v = *(const float4*)(x + (size_t)i * 4);
        short4v o;
        o[0] = (short)f2bf(v.x); o[1] = (short)f2bf(v.y);
        o[2] = (short)f2bf(v.z); o[3] = (short)f2bf(v.w);
        *(short4v*)(xb + (size_t)i * 4) = o;
    }
}

// ---------------------------------------------------------------- MFMA GEMM (bf16)
// C[r][:] = bf16( scale[r] * (A[r][:] @ W) ), A: bf16 [M,128], W: fp32 [128,128]
// block = 256 thr (4 waves). Strip = 64 rows x 128 cols.
// wave (rowHalf=wv>>1, colHalf=wv&1) computes 32 rows x 64 cols
// via 2x4 tiles of mfma_f32_16x16x32_bf16.
__global__ __launch_bounds__(256)
void gemm_mfma_kernel(const ushort* __restrict__ A, const float* __restrict__ W,
                      const float* __restrict__ scale, ushort* __restrict__ C,
                      int M, int nStrips)
{
    __shared__ ushort WT[128 * 132];   // [col][k], stride 132 ushorts (264 B) - conflict-free frag reads
    __shared__ ushort As[64 * 132];    // [row][k], stride 132
    __shared__ float  sScale[64];

    const int tid  = threadIdx.x;
    const int wv   = tid >> 6;
    const int lane = tid & 63;
    const int rowHalf = wv >> 1;
    const int colHalf = wv & 1;
    const int l15  = lane & 15;
    const int quad = lane >> 4;        // 0..3

    // stage WT = bf16(W)^T : W is [k][col] fp32
    for (int it = 0; it < 16; ++it) {
        int fid = tid + (it << 8);             // 0..4095
        int k   = fid >> 5;                    // 0..127
        int c4  = (fid & 31) << 2;             // 0..124
        float4 w = *(const float4*)(W + (size_t)k * FEAT + c4);
        WT[(c4 + 0) * 132 + k] = f2bf(w.x);
        WT[(c4 + 1) * 132 + k] = f2bf(w.y);
        WT[(c4 + 2) * 132 + k] = f2bf(w.z);
        WT[(c4 + 3) * 132 + k] = f2bf(w.w);
    }
    __syncthreads();

    // hoist B fragments: [ct][kst], col = colHalf*64 + ct*16 + l15, k = kst*32 + quad*8
    short8 bfrag[4][4];
#pragma unroll
    for (int ct = 0; ct < 4; ++ct) {
        int col = colHalf * 64 + ct * 16 + l15;
#pragma unroll
        for (int kst = 0; kst < 4; ++kst) {
            int k = kst * 32 + quad * 8;
            short4v lo = *(const short4v*)&WT[col * 132 + k];
            short4v hi = *(const short4v*)&WT[col * 132 + k + 4];
            bfrag[ct][kst] = __builtin_shufflevector(lo, hi, 0, 1, 2, 3, 4, 5, 6, 7);
        }
    }

    for (int s = blockIdx.x; s < nStrips; s += gridDim.x) {
        const int row0 = s << 6;
        __syncthreads();   // protect As / sScale from previous strip's readers

        // stage A strip: 64 rows x 128 k bf16 -> As (8B stores keep 264B stride legal)
#pragma unroll
        for (int it = 0; it < 4; ++it) {
            int fid = tid + (it << 8);         // 0..1023
            int r   = fid >> 4;                // 0..63
            int seg = (fid & 15) << 3;         // 0..120 step 8
            int grow = row0 + r;
            short4v lo = {0, 0, 0, 0}, hi = {0, 0, 0, 0};
            if (grow < M) {
                const ushort* p = A + (size_t)grow * FEAT + seg;
                lo = *(const short4v*)(p);
                hi = *(const short4v*)(p + 4);
            }
            *(short4v*)&As[r * 132 + seg]     = lo;
            *(short4v*)&As[r * 132 + seg + 4] = hi;
        }
        if (tid < 64) {
            int grow = row0 + tid;
            sScale[tid] = (grow < M) ? scale[grow] : 0.0f;
        }
        __syncthreads();

        f32x4 acc[2][4] = {};
#pragma unroll
        for (int kst = 0; kst < 4; ++kst) {
            int k = kst * 32 + quad * 8;
            short8 af[2];
#pragma unroll
            for (int rt = 0; rt < 2; ++rt) {
                int row = rowHalf * 32 + rt * 16 + l15;
                short4v lo = *(const short4v*)&As[row * 132 + k];
                short4v hi = *(const short4v*)&As[row * 132 + k + 4];
                af[rt] = __builtin_shufflevector(lo, hi, 0, 1, 2, 3, 4, 5, 6, 7);
            }
#pragma unroll
            for (int rt = 0; rt < 2; ++rt)
#pragma unroll
                for (int ct = 0; ct < 4; ++ct)
                    acc[rt][ct] = __builtin_amdgcn_mfma_f32_16x16x32_bf16(
                        af[rt], bfrag[ct][kst], acc[rt][ct], 0, 0, 0);
        }

        // epilogue: C/D layout col=lane&15, row=quad*4+reg
#pragma unroll
        for (int rt = 0; rt < 2; ++rt) {
            int rbase = rowHalf * 32 + rt * 16 + quad * 4;
#pragma unroll
            for (int reg = 0; reg < 4; ++reg) {
                int rl = rbase + reg;
                int grow = row0 + rl;
                if (grow < M) {
                    float sc = sScale[rl];
#pragma unroll
                    for (int ct = 0; ct < 4; ++ct) {
                        int col = colHalf * 64 + ct * 16 + l15;
                        C[(size_t)grow * FEAT + col] = f2bf(acc[rt][ct][reg] * sc);
                    }
                }
            }
        }
    }
}

// ---------------------------------------------------------------- gather + fused relu(agg*normIn + bias)
// out[n][:] = bf16( relu( (sum_{j} t[csrSrc[j]][:]) * normIn[n] + bias[:] ) )
// one half-wave (32 lanes x 4 feats) per node
__global__ __launch_bounds__(256)
void gather_kernel(const ushort* __restrict__ t, const int* __restrict__ rowStart,
                   const int* __restrict__ csrSrc, const float* __restrict__ normIn,
                   const float* __restrict__ bias, ushort* __restrict__ out, int N)
{
    const int hw   = threadIdx.x >> 5;
    const int lane = threadIdx.x & 31;
    const int node = blockIdx.x * 8 + hw;
    if (node >= N) return;
    const int s = rowStart[node];
    const int e = rowStart[node + 1];
    float a0 = 0.f, a1 = 0.f, a2 = 0.f, a3 = 0.f;
    for (int base = s; base < e; base += 32) {
        const int m = min(32, e - base);
        int idx = (base + lane < e) ? csrSrc[base + lane] : 0;
#pragma unroll 4
        for (int j = 0; j < m; ++j) {
            int srcn = __shfl(idx, j, 32);
            short4v v = *(const short4v*)(t + (size_t)srcn * FEAT + lane * 4);
            a0 += bf2f(v[0]); a1 += bf2f(v[1]); a2 += bf2f(v[2]); a3 += bf2f(v[3]);
        }
    }
    float ni = normIn[node];
    float4 b = *(const float4*)(bias + lane * 4);
    short4v o;
    o[0] = (short)f2bf(fmaxf(fmaf(a0, ni, b.x), 0.0f));
    o[1] = (short)f2bf(fmaxf(fmaf(a1, ni, b.y), 0.0f));
    o[2] = (short)f2bf(fmaxf(fmaf(a2, ni, b.z), 0.0f));
    o[3] = (short)f2bf(fmaxf(fmaf(a3, ni, b.w), 0.0f));
    *(short4v*)(out + (size_t)node * FEAT + lane * 4) = o;
}

// ---------------------------------------------------------------- column sum of bf16 h2
__global__ __launch_bounds__(256)
void colreduce_kernel(const ushort* __restrict__ h2, float* __restrict__ colsum, int N)
{
    const int c  = threadIdx.x & 127;
    const int rg = threadIdx.x >> 7;
    const int r0 = blockIdx.x * 256;
    const int rEnd = min(r0 + 256, N);
    float acc = 0.0f;
    for (int r = r0 + rg; r < rEnd; r += 2)
        acc += bf2f(h2[(size_t)r * FEAT + c]);
    __shared__ float sh[256];
    sh[threadIdx.x] = acc;
    __syncthreads();
    if (rg == 0) unsafeAtomicAdd(&colsum[c], sh[c] + sh[128 + c]);
}

// ---------------------------------------------------------------- final readout
__global__ __launch_bounds__(128)
void final_kernel(const float* __restrict__ colsum, const float* __restrict__ Wr,
                  const float* __restrict__ br, float* __restrict__ out, float invN)
{
    __shared__ float s0[128], s1[128];
    int j = threadIdx.x;
    float hg = colsum[j] * invN;
    s0[j] = hg * Wr[2 * j + 0];
    s1[j] = hg * Wr[2 * j + 1];
    __syncthreads();
    for (int off = 64; off > 0; off >>= 1) {
        if (j < off) { s0[j] += s0[j + off]; s1[j] += s1[j + off]; }
        __syncthreads();
    }
    if (j == 0) {
        out[0] = s0[0] + br[0];
        out[1] = s1[0] + br[1];
    }
}

// ---------------------------------------------------------------- launch
extern "C" void kernel_launch(void* const* d_in, const int* in_sizes, int n_in,
                              void* d_out, int out_size, void* d_ws, size_t ws_size,
                              hipStream_t stream)
{
    const float* x   = (const float*)d_in[0];
    const int*   src = (const int*)d_in[1];
    const int*   dst = (const int*)d_in[2];
    const float* W1  = (const float*)d_in[3];
    const float* b1  = (const float*)d_in[4];
    const float* W2  = (const float*)d_in[5];
    const float* b2  = (const float*)d_in[6];
    const float* Wr  = (const float*)d_in[7];
    const float* br  = (const float*)d_in[8];
    float* out = (float*)d_out;

    const int N = in_sizes[0] / FEAT;         // 50000
    const int E = in_sizes[1];                // 640000
    const int NP = ((N + 255) / 256) * 256;
    const int NB = (N + 255) / 256;           // <= 256

    // workspace layout
    char* p = (char*)d_ws;
    int*   cntOut   = (int*)p;       p += (size_t)NP * 4;
    int*   cntIn    = (int*)p;       p += (size_t)NP * 4;
    float* colsum   = (float*)p;     p += 256 * 4;
    int*   blockSums= (int*)p;       p += 256 * 4;
    float* normOut  = (float*)p;     p += (size_t)NP * 4;
    float* normIn   = (float*)p;     p += (size_t)NP * 4;
    int*   rowStart = (int*)p;       p += (size_t)(NP + 64) * 4;
    int*   csrSrc   = (int*)p;       p += (size_t)E * 4;
    ushort* xb      = (ushort*)p;    p += (size_t)N * FEAT * 2;
    ushort* bufT    = (ushort*)p;    p += (size_t)N * FEAT * 2;
    ushort* bufH    = (ushort*)p;    p += (size_t)N * FEAT * 2;

    int* cursor = cntOut;   // reuse after scan3 (cntOut consumed there)

    hipMemsetAsync(d_ws, 0, (size_t)(2 * NP + 512) * 4, stream);

    deg_kernel<<<(E + 255) / 256, 256, 0, stream>>>(src, dst, cntOut, cntIn, E);
    scan1_kernel<<<NB, 256, 0, stream>>>(cntIn, blockSums, N);
    scan2_kernel<<<1, 256, 0, stream>>>(blockSums, rowStart + N, NB);
    scan3_kernel<<<NB, 256, 0, stream>>>(cntIn, cntOut, blockSums, rowStart, cursor,
                                         normOut, normIn, N);
    fill_kernel<<<(E + 255) / 256, 256, 0, stream>>>(src, dst, cursor, csrSrc, E);

    convert_kernel<<<(N * FEAT / 4 + 255) / 256, 256, 0, stream>>>(x, xb, N * FEAT / 4);

    const int nStrips = (N + 63) / 64;
    const int gathBlocks = (N + 7) / 8;

    // layer 1
    gemm_mfma_kernel<<<256, 256, 0, stream>>>(xb, W1, normOut, bufT, N, nStrips);
    gather_kernel<<<gathBlocks, 256, 0, stream>>>(bufT, rowStart, csrSrc, normIn, b1, bufH, N);

    // layer 2
    gemm_mfma_kernel<<<256, 256, 0, stream>>>(bufH, W2, normOut, bufT, N, nStrips);
    gather_kernel<<<gathBlocks, 256, 0, stream>>>(bufT, rowStart, csrSrc, normIn, b2, bufH, N);

    // readout
    colreduce_kernel<<<NB, 256, 0, stream>>>(bufH, colsum, N);
    final_kernel<<<1, 128, 0, stream>>>(colsum, Wr, br, out, 1.0f / (float)N);
}

// Round 4
// 308.371 us; speedup vs baseline: 7.8433x; 1.0321x over previous
//
#include <hip/hip_runtime.h>
#include <hip/hip_bf16.h>

#define FEAT 128
#define RBITS 14
#define RSIZE 16384          // partition width (64 KB LDS of u32)
#define NCHUNK 32            // edge chunks

typedef __attribute__((ext_vector_type(8))) short short8;
typedef __attribute__((ext_vector_type(4))) short short4v;
typedef __attribute__((ext_vector_type(4))) float f32x4;

__device__ __forceinline__ ushort f2bf(float f) {
    union { float f; unsigned u; } v; v.f = f;
    unsigned u = v.u;
    unsigned r = 0x7fffu + ((u >> 16) & 1u);
    return (ushort)((u + r) >> 16);
}
__device__ __forceinline__ float bf2f(short s) {
    union { unsigned u; float f; } v;
    v.u = ((unsigned)(ushort)s) << 16;
    return v.f;
}

// ---------------------------------------------------------------- A: partial histograms (LDS atomics only)
// grid (NCHUNK, P, 2): z=0 -> histogram of src, z=1 -> histogram of dst
// partial[job][p][c][r], written in full (no global pre-zero needed)
__global__ __launch_bounds__(256)
void hist_kernel(const int* __restrict__ src, const int* __restrict__ dst,
                 unsigned* __restrict__ partial, int E, int CS)
{
    __shared__ unsigned hist[RSIZE];
    const int c = blockIdx.x, p = blockIdx.y, job = blockIdx.z;
    const int* __restrict__ idx = job ? dst : src;
    for (int r = threadIdx.x; r < RSIZE; r += 256) hist[r] = 0;
    __syncthreads();
    const int e0 = c * CS, e1 = min(E, e0 + CS);
    for (int e = e0 + threadIdx.x; e < e1; e += 256) {
        int v = idx[e];
        if ((v >> RBITS) == p) atomicAdd(&hist[v & (RSIZE - 1)], 1u);
    }
    __syncthreads();
    unsigned* out = partial +
        (((size_t)job * gridDim.y + p) * NCHUNK + c) * RSIZE;
    for (int r = threadIdx.x; r < RSIZE; r += 256) out[r] = hist[r];
}

// ---------------------------------------------------------------- B: merge partials -> degrees/norms, chunk offsets
// partialIn is overwritten in place with per-chunk EXCLUSIVE offsets.
__global__ __launch_bounds__(256)
void merge_kernel(unsigned* __restrict__ partialOut, unsigned* __restrict__ partialIn,
                  int* __restrict__ cntIn, float* __restrict__ normOut,
                  float* __restrict__ normIn, int N)
{
    int n = blockIdx.x * 256 + threadIdx.x;
    if (n >= N) return;
    const int p = n >> RBITS, r = n & (RSIZE - 1);
    const size_t base = (size_t)p * NCHUNK * RSIZE + r;
    unsigned so = 0;
#pragma unroll 8
    for (int c = 0; c < NCHUNK; ++c) so += partialOut[base + (size_t)c * RSIZE];
    unsigned off = 0;
#pragma unroll 8
    for (int c = 0; c < NCHUNK; ++c) {
        size_t i = base + (size_t)c * RSIZE;
        unsigned t = partialIn[i];
        partialIn[i] = off;
        off += t;
    }
    cntIn[n]   = (int)off;
    normIn[n]  = off ? rsqrtf((float)off) : 0.0f;
    normOut[n] = so  ? rsqrtf((float)so)  : 0.0f;
}

// ---------------------------------------------------------------- scan level 1: per-block sums of cntIn
__global__ __launch_bounds__(256)
void scan1_kernel(const int* __restrict__ cnt, int* __restrict__ blockSums, int N)
{
    __shared__ int sh[256];
    int i = blockIdx.x * 256 + threadIdx.x;
    sh[threadIdx.x] = (i < N) ? cnt[i] : 0;
    __syncthreads();
    for (int off = 128; off > 0; off >>= 1) {
        if (threadIdx.x < off) sh[threadIdx.x] += sh[threadIdx.x + off];
        __syncthreads();
    }
    if (threadIdx.x == 0) blockSums[blockIdx.x] = sh[0];
}

// ---------------------------------------------------------------- rowStart: local scan of blockSums + local scan of cntIn
__global__ __launch_bounds__(256)
void rowstart_kernel(const int* __restrict__ cntIn, const int* __restrict__ blockSums,
                     int* __restrict__ rowStart, int N, int NB, int E)
{
    __shared__ int bs[256];
    __shared__ int bse[256];
    __shared__ int sh[256];
    const int t = threadIdx.x;
    int bv = (t < NB) ? blockSums[t] : 0;
    bs[t] = bv;
    __syncthreads();
    for (int off = 1; off < 256; off <<= 1) {
        int u = (t >= off) ? bs[t - off] : 0;
        __syncthreads();
        bs[t] += u;
        __syncthreads();
    }
    bse[t] = bs[t] - bv;            // exclusive block prefix
    __syncthreads();

    const int i = blockIdx.x * 256 + t;
    int v = (i < N) ? cntIn[i] : 0;
    sh[t] = v;
    __syncthreads();
    for (int off = 1; off < 256; off <<= 1) {
        int u = (t >= off) ? sh[t - off] : 0;
        __syncthreads();
        sh[t] += u;
        __syncthreads();
    }
    if (i < N) rowStart[i] = bse[blockIdx.x] + sh[t] - v;
    if (blockIdx.x == 0 && t == 0) rowStart[N] = E;   // total = E always
}

// ---------------------------------------------------------------- fill: LDS cursor counting sort (no global atomics)
// grid (NCHUNK, P)
__global__ __launch_bounds__(256)
void fill_kernel(const int* __restrict__ src, const int* __restrict__ dst,
                 const int* __restrict__ rowStart, const unsigned* __restrict__ chunkOff,
                 int* __restrict__ csrSrc, int N, int E, int CS)
{
    __shared__ unsigned cursor[RSIZE];
    const int c = blockIdx.x, p = blockIdx.y;
    const unsigned* co = chunkOff + ((size_t)p * NCHUNK + c) * RSIZE;
    for (int r = threadIdx.x; r < RSIZE; r += 256) {
        int n = (p << RBITS) + r;
        cursor[r] = (n < N) ? (unsigned)rowStart[n] + co[r] : 0u;
    }
    __syncthreads();
    const int e0 = c * CS, e1 = min(E, e0 + CS);
    for (int e = e0 + threadIdx.x; e < e1; e += 256) {
        int d = dst[e];
        if ((d >> RBITS) == p) {
            unsigned pos = atomicAdd(&cursor[d & (RSIZE - 1)], 1u);
            csrSrc[pos] = src[e];
        }
    }
}

// ---------------------------------------------------------------- MFMA GEMM (bf16), optional fp32 input (converts inline)
// C[r][:] = bf16( scale[r] * (A[r][:] @ W) ), W: fp32 [128,128]
__global__ __launch_bounds__(256)
void gemm_mfma_f32in_stub(); // (no-op decl to keep template below adjacent)

template<bool F32IN>
__global__ __launch_bounds__(256)
void gemm_mfma_kernel(const void* __restrict__ Ain, const float* __restrict__ W,
                      const float* __restrict__ scale, ushort* __restrict__ C,
                      int M, int nStrips)
{
    __shared__ ushort WT[128 * 132];   // [col][k]
    __shared__ ushort As[64 * 132];    // [row][k]
    __shared__ float  sScale[64];

    const int tid  = threadIdx.x;
    const int wv   = tid >> 6;
    const int lane = tid & 63;
    const int rowHalf = wv >> 1;
    const int colHalf = wv & 1;
    const int l15  = lane & 15;
    const int quad = lane >> 4;

    // stage WT = bf16(W)^T
    for (int it = 0; it < 16; ++it) {
        int fid = tid + (it << 8);
        int k   = fid >> 5;
        int c4  = (fid & 31) << 2;
        float4 w = *(const float4*)(W + (size_t)k * FEAT + c4);
        WT[(c4 + 0) * 132 + k] = f2bf(w.x);
        WT[(c4 + 1) * 132 + k] = f2bf(w.y);
        WT[(c4 + 2) * 132 + k] = f2bf(w.z);
        WT[(c4 + 3) * 132 + k] = f2bf(w.w);
    }
    __syncthreads();

    short8 bfrag[4][4];
#pragma unroll
    for (int ct = 0; ct < 4; ++ct) {
        int col = colHalf * 64 + ct * 16 + l15;
#pragma unroll
        for (int kst = 0; kst < 4; ++kst) {
            int k = kst * 32 + quad * 8;
            short4v lo = *(const short4v*)&WT[col * 132 + k];
            short4v hi = *(const short4v*)&WT[col * 132 + k + 4];
            bfrag[ct][kst] = __builtin_shufflevector(lo, hi, 0, 1, 2, 3, 4, 5, 6, 7);
        }
    }

    for (int s = blockIdx.x; s < nStrips; s += gridDim.x) {
        const int row0 = s << 6;
        __syncthreads();

#pragma unroll
        for (int it = 0; it < 4; ++it) {
            int fid = tid + (it << 8);
            int r   = fid >> 4;
            int seg = (fid & 15) << 3;
            int grow = row0 + r;
            short4v lo = {0, 0, 0, 0}, hi = {0, 0, 0, 0};
            if (grow < M) {
                if (F32IN) {
                    const float* pa = (const float*)Ain + (size_t)grow * FEAT + seg;
                    float4 u0 = *(const float4*)(pa);
                    float4 u1 = *(const float4*)(pa + 4);
                    lo[0] = (short)f2bf(u0.x); lo[1] = (short)f2bf(u0.y);
                    lo[2] = (short)f2bf(u0.z); lo[3] = (short)f2bf(u0.w);
                    hi[0] = (short)f2bf(u1.x); hi[1] = (short)f2bf(u1.y);
                    hi[2] = (short)f2bf(u1.z); hi[3] = (short)f2bf(u1.w);
                } else {
                    const ushort* pa = (const ushort*)Ain + (size_t)grow * FEAT + seg;
                    lo = *(const short4v*)(pa);
                    hi = *(const short4v*)(pa + 4);
                }
            }
            *(short4v*)&As[r * 132 + seg]     = lo;
            *(short4v*)&As[r * 132 + seg + 4] = hi;
        }
        if (tid < 64) {
            int grow = row0 + tid;
            sScale[tid] = (grow < M) ? scale[grow] : 0.0f;
        }
        __syncthreads();

        f32x4 acc[2][4] = {};
#pragma unroll
        for (int kst = 0; kst < 4; ++kst) {
            int k = kst * 32 + quad * 8;
            short8 af[2];
#pragma unroll
            for (int rt = 0; rt < 2; ++rt) {
                int row = rowHalf * 32 + rt * 16 + l15;
                short4v lo = *(const short4v*)&As[row * 132 + k];
                short4v hi = *(const short4v*)&As[row * 132 + k + 4];
                af[rt] = __builtin_shufflevector(lo, hi, 0, 1, 2, 3, 4, 5, 6, 7);
            }
#pragma unroll
            for (int rt = 0; rt < 2; ++rt)
#pragma unroll
                for (int ct = 0; ct < 4; ++ct)
                    acc[rt][ct] = __builtin_amdgcn_mfma_f32_16x16x32_bf16(
                        af[rt], bfrag[ct][kst], acc[rt][ct], 0, 0, 0);
        }

#pragma unroll
        for (int rt = 0; rt < 2; ++rt) {
            int rbase = rowHalf * 32 + rt * 16 + quad * 4;
#pragma unroll
            for (int reg = 0; reg < 4; ++reg) {
                int rl = rbase + reg;
                int grow = row0 + rl;
                if (grow < M) {
                    float sc = sScale[rl];
#pragma unroll
                    for (int ct = 0; ct < 4; ++ct) {
                        int col = colHalf * 64 + ct * 16 + l15;
                        C[(size_t)grow * FEAT + col] = f2bf(acc[rt][ct][reg] * sc);
                    }
                }
            }
        }
    }
}

// ---------------------------------------------------------------- gather + fused relu(agg*normIn + bias)
__global__ __launch_bounds__(256)
void gather_kernel(const ushort* __restrict__ t, const int* __restrict__ rowStart,
                   const int* __restrict__ csrSrc, const float* __restrict__ normIn,
                   const float* __restrict__ bias, ushort* __restrict__ out, int N)
{
    const int hw   = threadIdx.x >> 5;
    const int lane = threadIdx.x & 31;
    const int node = blockIdx.x * 8 + hw;
    if (node >= N) return;
    const int s = rowStart[node];
    const int e = rowStart[node + 1];
    float a0 = 0.f, a1 = 0.f, a2 = 0.f, a3 = 0.f;
    for (int base = s; base < e; base += 32) {
        const int m = min(32, e - base);
        int idx = (base + lane < e) ? csrSrc[base + lane] : 0;
#pragma unroll 4
        for (int j = 0; j < m; ++j) {
            int srcn = __shfl(idx, j, 32);
            short4v v = *(const short4v*)(t + (size_t)srcn * FEAT + lane * 4);
            a0 += bf2f(v[0]); a1 += bf2f(v[1]); a2 += bf2f(v[2]); a3 += bf2f(v[3]);
        }
    }
    float ni = normIn[node];
    float4 b = *(const float4*)(bias + lane * 4);
    short4v o;
    o[0] = (short)f2bf(fmaxf(fmaf(a0, ni, b.x), 0.0f));
    o[1] = (short)f2bf(fmaxf(fmaf(a1, ni, b.y), 0.0f));
    o[2] = (short)f2bf(fmaxf(fmaf(a2, ni, b.z), 0.0f));
    o[3] = (short)f2bf(fmaxf(fmaf(a3, ni, b.w), 0.0f));
    *(short4v*)(out + (size_t)node * FEAT + lane * 4) = o;
}

// ---------------------------------------------------------------- column sum of bf16 h2
__global__ __launch_bounds__(256)
void colreduce_kernel(const ushort* __restrict__ h2, float* __restrict__ colsum, int N)
{
    const int c  = threadIdx.x & 127;
    const int rg = threadIdx.x >> 7;
    const int r0 = blockIdx.x * 256;
    const int rEnd = min(r0 + 256, N);
    float acc = 0.0f;
    for (int r = r0 + rg; r < rEnd; r += 2)
        acc += bf2f(h2[(size_t)r * FEAT + c]);
    __shared__ float sh[256];
    sh[threadIdx.x] = acc;
    __syncthreads();
    if (rg == 0) unsafeAtomicAdd(&colsum[c], sh[c] + sh[128 + c]);
}

// ---------------------------------------------------------------- final readout
__global__ __launch_bounds__(128)
void final_kernel(const float* __restrict__ colsum, const float* __restrict__ Wr,
                  const float* __restrict__ br, float* __restrict__ out, float invN)
{
    __shared__ float s0[128], s1[128];
    int j = threadIdx.x;
    float hg = colsum[j] * invN;
    s0[j] = hg * Wr[2 * j + 0];
    s1[j] = hg * Wr[2 * j + 1];
    __syncthreads();
    for (int off = 64; off > 0; off >>= 1) {
        if (j < off) { s0[j] += s0[j + off]; s1[j] += s1[j + off]; }
        __syncthreads();
    }
    if (j == 0) {
        out[0] = s0[0] + br[0];
        out[1] = s1[0] + br[1];
    }
}

// ---------------------------------------------------------------- launch
extern "C" void kernel_launch(void* const* d_in, const int* in_sizes, int n_in,
                              void* d_out, int out_size, void* d_ws, size_t ws_size,
                              hipStream_t stream)
{
    const float* x   = (const float*)d_in[0];
    const int*   src = (const int*)d_in[1];
    const int*   dst = (const int*)d_in[2];
    const float* W1  = (const float*)d_in[3];
    const float* b1  = (const float*)d_in[4];
    const float* W2  = (const float*)d_in[5];
    const float* b2  = (const float*)d_in[6];
    const float* Wr  = (const float*)d_in[7];
    const float* br  = (const float*)d_in[8];
    float* out = (float*)d_out;

    const int N = in_sizes[0] / FEAT;         // 50000
    const int E = in_sizes[1];                // 640000
    const int NP = ((N + 255) / 256) * 256;
    const int NB = (N + 255) / 256;           // <= 256
    const int P  = (N + RSIZE - 1) / RSIZE;   // 4
    const int CS = (E + NCHUNK - 1) / NCHUNK; // 20000

    // workspace layout
    char* p = (char*)d_ws;
    unsigned* partial   = (unsigned*)p;  p += (size_t)2 * P * NCHUNK * RSIZE * 4; // [job][p][c][r]
    float*  colsum    = (float*)p;       p += 256 * 4;
    int*    blockSums = (int*)p;         p += 256 * 4;
    int*    cntIn     = (int*)p;         p += (size_t)NP * 4;
    float*  normOut   = (float*)p;       p += (size_t)NP * 4;
    float*  normIn    = (float*)p;       p += (size_t)NP * 4;
    int*    rowStart  = (int*)p;         p += (size_t)(NP + 64) * 4;
    int*    csrSrc    = (int*)p;         p += (size_t)E * 4;
    ushort* bufT      = (ushort*)p;      p += (size_t)N * FEAT * 2;
    ushort* bufH      = (ushort*)p;      p += (size_t)N * FEAT * 2;

    unsigned* partialOut = partial;                                  // job 0 (src)
    unsigned* partialIn  = partial + (size_t)P * NCHUNK * RSIZE;     // job 1 (dst)

    hipMemsetAsync(colsum, 0, 256 * 4, stream);

    // CSR + degree pipeline (no memory-side atomics)
    hist_kernel<<<dim3(NCHUNK, P, 2), 256, 0, stream>>>(src, dst, partial, E, CS);
    merge_kernel<<<NB, 256, 0, stream>>>(partialOut, partialIn, cntIn, normOut, normIn, N);
    scan1_kernel<<<NB, 256, 0, stream>>>(cntIn, blockSums, N);
    rowstart_kernel<<<NB, 256, 0, stream>>>(cntIn, blockSums, rowStart, N, NB, E);
    fill_kernel<<<dim3(NCHUNK, P), 256, 0, stream>>>(src, dst, rowStart, partialIn, csrSrc, N, E, CS);

    const int nStrips = (N + 63) / 64;
    const int gathBlocks = (N + 7) / 8;

    // layer 1 (x fp32 consumed directly, converted inline)
    gemm_mfma_kernel<true><<<256, 256, 0, stream>>>((const void*)x, W1, normOut, bufT, N, nStrips);
    gather_kernel<<<gathBlocks, 256, 0, stream>>>(bufT, rowStart, csrSrc, normIn, b1, bufH, N);

    // layer 2
    gemm_mfma_kernel<false><<<256, 256, 0, stream>>>((const void*)bufH, W2, normOut, bufT, N, nStrips);
    gather_kernel<<<gathBlocks, 256, 0, stream>>>(bufT, rowStart, csrSrc, normIn, b2, bufH, N);

    // readout
    colreduce_kernel<<<NB, 256, 0, stream>>>(bufH, colsum, N);
    final_kernel<<<1, 128, 0, stream>>>(colsum, Wr, br, out, 1.0f / (float)N);
}

// Round 5
// 260.004 us; speedup vs baseline: 9.3024x; 1.1860x over previous
//
#include <hip/hip_runtime.h>
#include <hip/hip_bf16.h>

#define FEAT 128
#define RBITS 12
#define RSIZE 4096           // partition width (16 KB LDS of u32)
#define NCHUNK 64            // edge chunks

typedef __attribute__((ext_vector_type(8))) short short8;
typedef __attribute__((ext_vector_type(4))) short short4v;
typedef __attribute__((ext_vector_type(4))) float f32x4;

__device__ __forceinline__ ushort f2bf(float f) {
    union { float f; unsigned u; } v; v.f = f;
    unsigned u = v.u;
    unsigned r = 0x7fffu + ((u >> 16) & 1u);
    return (ushort)((u + r) >> 16);
}
__device__ __forceinline__ float bf2f(short s) {
    union { unsigned u; float f; } v;
    v.u = ((unsigned)(ushort)s) << 16;
    return v.f;
}

// ---------------------------------------------------------------- A: partial histograms (LDS atomics only)
// grid (NCHUNK, P, 2): z=0 -> histogram of src, z=1 -> histogram of dst
__global__ __launch_bounds__(256)
void hist_kernel(const int* __restrict__ src, const int* __restrict__ dst,
                 unsigned* __restrict__ partial, int E, int CS)
{
    __shared__ unsigned hist[RSIZE];
    const int c = blockIdx.x, p = blockIdx.y, job = blockIdx.z;
    const int* __restrict__ idx = job ? dst : src;
    for (int r = threadIdx.x; r < RSIZE; r += 256) hist[r] = 0;
    __syncthreads();
    const int e0 = c * CS, e1 = min(E, e0 + CS);
    for (int e = e0 + threadIdx.x; e < e1; e += 256) {
        int v = idx[e];
        if ((v >> RBITS) == p) atomicAdd(&hist[v & (RSIZE - 1)], 1u);
    }
    __syncthreads();
    unsigned* out = partial +
        (((size_t)job * gridDim.y + p) * NCHUNK + c) * RSIZE;
    for (int r = threadIdx.x; r < RSIZE; r += 256) out[r] = hist[r];
}

// ---------------------------------------------------------------- B: merge partials -> degrees/norms, chunk offsets
// partialIn is overwritten in place with per-chunk EXCLUSIVE offsets.
__global__ __launch_bounds__(256)
void merge_kernel(unsigned* __restrict__ partialOut, unsigned* __restrict__ partialIn,
                  int* __restrict__ cntIn, float* __restrict__ normOut,
                  float* __restrict__ normIn, int N)
{
    int n = blockIdx.x * 256 + threadIdx.x;
    if (n >= N) return;
    const int p = n >> RBITS, r = n & (RSIZE - 1);
    const size_t base = (size_t)p * NCHUNK * RSIZE + r;
    unsigned so = 0;
#pragma unroll 8
    for (int c = 0; c < NCHUNK; ++c) so += partialOut[base + (size_t)c * RSIZE];
    unsigned off = 0;
#pragma unroll 8
    for (int c = 0; c < NCHUNK; ++c) {
        size_t i = base + (size_t)c * RSIZE;
        unsigned t = partialIn[i];
        partialIn[i] = off;
        off += t;
    }
    cntIn[n]   = (int)off;
    normIn[n]  = off ? rsqrtf((float)off) : 0.0f;
    normOut[n] = so  ? rsqrtf((float)so)  : 0.0f;
}

// ---------------------------------------------------------------- scan level 1: per-block sums of cntIn
__global__ __launch_bounds__(256)
void scan1_kernel(const int* __restrict__ cnt, int* __restrict__ blockSums, int N)
{
    __shared__ int sh[256];
    int i = blockIdx.x * 256 + threadIdx.x;
    sh[threadIdx.x] = (i < N) ? cnt[i] : 0;
    __syncthreads();
    for (int off = 128; off > 0; off >>= 1) {
        if (threadIdx.x < off) sh[threadIdx.x] += sh[threadIdx.x + off];
        __syncthreads();
    }
    if (threadIdx.x == 0) blockSums[blockIdx.x] = sh[0];
}

// ---------------------------------------------------------------- rowStart
__global__ __launch_bounds__(256)
void rowstart_kernel(const int* __restrict__ cntIn, const int* __restrict__ blockSums,
                     int* __restrict__ rowStart, int N, int NB, int E)
{
    __shared__ int bs[256];
    __shared__ int bse[256];
    __shared__ int sh[256];
    const int t = threadIdx.x;
    int bv = (t < NB) ? blockSums[t] : 0;
    bs[t] = bv;
    __syncthreads();
    for (int off = 1; off < 256; off <<= 1) {
        int u = (t >= off) ? bs[t - off] : 0;
        __syncthreads();
        bs[t] += u;
        __syncthreads();
    }
    bse[t] = bs[t] - bv;
    __syncthreads();

    const int i = blockIdx.x * 256 + t;
    int v = (i < N) ? cntIn[i] : 0;
    sh[t] = v;
    __syncthreads();
    for (int off = 1; off < 256; off <<= 1) {
        int u = (t >= off) ? sh[t - off] : 0;
        __syncthreads();
        sh[t] += u;
        __syncthreads();
    }
    if (i < N) rowStart[i] = bse[blockIdx.x] + sh[t] - v;
    if (blockIdx.x == 0 && t == 0) rowStart[N] = E;
}

// ---------------------------------------------------------------- fill: LDS cursor counting sort
// grid (NCHUNK, P)
__global__ __launch_bounds__(256)
void fill_kernel(const int* __restrict__ src, const int* __restrict__ dst,
                 const int* __restrict__ rowStart, const unsigned* __restrict__ chunkOff,
                 int* __restrict__ csrSrc, int N, int E, int CS)
{
    __shared__ unsigned cursor[RSIZE];
    const int c = blockIdx.x, p = blockIdx.y;
    const unsigned* co = chunkOff + ((size_t)p * NCHUNK + c) * RSIZE;
    for (int r = threadIdx.x; r < RSIZE; r += 256) {
        int n = (p << RBITS) + r;
        cursor[r] = (n < N) ? (unsigned)rowStart[n] + co[r] : 0u;
    }
    __syncthreads();
    const int e0 = c * CS, e1 = min(E, e0 + CS);
    for (int e = e0 + threadIdx.x; e < e1; e += 256) {
        int d = dst[e];
        if ((d >> RBITS) == p) {
            unsigned pos = atomicAdd(&cursor[d & (RSIZE - 1)], 1u);
            csrSrc[pos] = src[e];
        }
    }
}

// ---------------------------------------------------------------- MFMA GEMM (bf16), optional fp32 input
template<bool F32IN>
__global__ __launch_bounds__(256)
void gemm_mfma_kernel(const void* __restrict__ Ain, const float* __restrict__ W,
                      const float* __restrict__ scale, ushort* __restrict__ C,
                      int M, int nStrips)
{
    __shared__ ushort WT[128 * 132];   // [col][k]
    __shared__ ushort As[64 * 132];    // [row][k]
    __shared__ float  sScale[64];

    const int tid  = threadIdx.x;
    const int wv   = tid >> 6;
    const int lane = tid & 63;
    const int rowHalf = wv >> 1;
    const int colHalf = wv & 1;
    const int l15  = lane & 15;
    const int quad = lane >> 4;

    for (int it = 0; it < 16; ++it) {
        int fid = tid + (it << 8);
        int k   = fid >> 5;
        int c4  = (fid & 31) << 2;
        float4 w = *(const float4*)(W + (size_t)k * FEAT + c4);
        WT[(c4 + 0) * 132 + k] = f2bf(w.x);
        WT[(c4 + 1) * 132 + k] = f2bf(w.y);
        WT[(c4 + 2) * 132 + k] = f2bf(w.z);
        WT[(c4 + 3) * 132 + k] = f2bf(w.w);
    }
    __syncthreads();

    short8 bfrag[4][4];
#pragma unroll
    for (int ct = 0; ct < 4; ++ct) {
        int col = colHalf * 64 + ct * 16 + l15;
#pragma unroll
        for (int kst = 0; kst < 4; ++kst) {
            int k = kst * 32 + quad * 8;
            short4v lo = *(const short4v*)&WT[col * 132 + k];
            short4v hi = *(const short4v*)&WT[col * 132 + k + 4];
            bfrag[ct][kst] = __builtin_shufflevector(lo, hi, 0, 1, 2, 3, 4, 5, 6, 7);
        }
    }

    for (int s = blockIdx.x; s < nStrips; s += gridDim.x) {
        const int row0 = s << 6;
        __syncthreads();

#pragma unroll
        for (int it = 0; it < 4; ++it) {
            int fid = tid + (it << 8);
            int r   = fid >> 4;
            int seg = (fid & 15) << 3;
            int grow = row0 + r;
            short4v lo = {0, 0, 0, 0}, hi = {0, 0, 0, 0};
            if (grow < M) {
                if (F32IN) {
                    const float* pa = (const float*)Ain + (size_t)grow * FEAT + seg;
                    float4 u0 = *(const float4*)(pa);
                    float4 u1 = *(const float4*)(pa + 4);
                    lo[0] = (short)f2bf(u0.x); lo[1] = (short)f2bf(u0.y);
                    lo[2] = (short)f2bf(u0.z); lo[3] = (short)f2bf(u0.w);
                    hi[0] = (short)f2bf(u1.x); hi[1] = (short)f2bf(u1.y);
                    hi[2] = (short)f2bf(u1.z); hi[3] = (short)f2bf(u1.w);
                } else {
                    const ushort* pa = (const ushort*)Ain + (size_t)grow * FEAT + seg;
                    lo = *(const short4v*)(pa);
                    hi = *(const short4v*)(pa + 4);
                }
            }
            *(short4v*)&As[r * 132 + seg]     = lo;
            *(short4v*)&As[r * 132 + seg + 4] = hi;
        }
        if (tid < 64) {
            int grow = row0 + tid;
            sScale[tid] = (grow < M) ? scale[grow] : 0.0f;
        }
        __syncthreads();

        f32x4 acc[2][4] = {};
#pragma unroll
        for (int kst = 0; kst < 4; ++kst) {
            int k = kst * 32 + quad * 8;
            short8 af[2];
#pragma unroll
            for (int rt = 0; rt < 2; ++rt) {
                int row = rowHalf * 32 + rt * 16 + l15;
                short4v lo = *(const short4v*)&As[row * 132 + k];
                short4v hi = *(const short4v*)&As[row * 132 + k + 4];
                af[rt] = __builtin_shufflevector(lo, hi, 0, 1, 2, 3, 4, 5, 6, 7);
            }
#pragma unroll
            for (int rt = 0; rt < 2; ++rt)
#pragma unroll
                for (int ct = 0; ct < 4; ++ct)
                    acc[rt][ct] = __builtin_amdgcn_mfma_f32_16x16x32_bf16(
                        af[rt], bfrag[ct][kst], acc[rt][ct], 0, 0, 0);
        }

#pragma unroll
        for (int rt = 0; rt < 2; ++rt) {
            int rbase = rowHalf * 32 + rt * 16 + quad * 4;
#pragma unroll
            for (int reg = 0; reg < 4; ++reg) {
                int rl = rbase + reg;
                int grow = row0 + rl;
                if (grow < M) {
                    float sc = sScale[rl];
#pragma unroll
                    for (int ct = 0; ct < 4; ++ct) {
                        int col = colHalf * 64 + ct * 16 + l15;
                        C[(size_t)grow * FEAT + col] = f2bf(acc[rt][ct][reg] * sc);
                    }
                }
            }
        }
    }
}

// ---------------------------------------------------------------- gather + fused relu(agg*normIn + bias)
__global__ __launch_bounds__(256)
void gather_kernel(const ushort* __restrict__ t, const int* __restrict__ rowStart,
                   const int* __restrict__ csrSrc, const float* __restrict__ normIn,
                   const float* __restrict__ bias, ushort* __restrict__ out, int N)
{
    const int hw   = threadIdx.x >> 5;
    const int lane = threadIdx.x & 31;
    const int node = blockIdx.x * 8 + hw;
    if (node >= N) return;
    const int s = rowStart[node];
    const int e = rowStart[node + 1];
    float a0 = 0.f, a1 = 0.f, a2 = 0.f, a3 = 0.f;
    for (int base = s; base < e; base += 32) {
        const int m = min(32, e - base);
        int idx = (base + lane < e) ? csrSrc[base + lane] : 0;
        int j = 0;
        for (; j + 4 <= m; j += 4) {
            int s0 = __shfl(idx, j,     32);
            int s1 = __shfl(idx, j + 1, 32);
            int s2 = __shfl(idx, j + 2, 32);
            int s3 = __shfl(idx, j + 3, 32);
            short4v v0 = *(const short4v*)(t + (size_t)s0 * FEAT + lane * 4);
            short4v v1 = *(const short4v*)(t + (size_t)s1 * FEAT + lane * 4);
            short4v v2 = *(const short4v*)(t + (size_t)s2 * FEAT + lane * 4);
            short4v v3 = *(const short4v*)(t + (size_t)s3 * FEAT + lane * 4);
            a0 += bf2f(v0[0]) + bf2f(v1[0]) + bf2f(v2[0]) + bf2f(v3[0]);
            a1 += bf2f(v0[1]) + bf2f(v1[1]) + bf2f(v2[1]) + bf2f(v3[1]);
            a2 += bf2f(v0[2]) + bf2f(v1[2]) + bf2f(v2[2]) + bf2f(v3[2]);
            a3 += bf2f(v0[3]) + bf2f(v1[3]) + bf2f(v2[3]) + bf2f(v3[3]);
        }
        for (; j < m; ++j) {
            int srcn = __shfl(idx, j, 32);
            short4v v = *(const short4v*)(t + (size_t)srcn * FEAT + lane * 4);
            a0 += bf2f(v[0]); a1 += bf2f(v[1]); a2 += bf2f(v[2]); a3 += bf2f(v[3]);
        }
    }
    float ni = normIn[node];
    float4 b = *(const float4*)(bias + lane * 4);
    short4v o;
    o[0] = (short)f2bf(fmaxf(fmaf(a0, ni, b.x), 0.0f));
    o[1] = (short)f2bf(fmaxf(fmaf(a1, ni, b.y), 0.0f));
    o[2] = (short)f2bf(fmaxf(fmaf(a2, ni, b.z), 0.0f));
    o[3] = (short)f2bf(fmaxf(fmaf(a3, ni, b.w), 0.0f));
    *(short4v*)(out + (size_t)node * FEAT + lane * 4) = o;
}

// ---------------------------------------------------------------- column sum of bf16 h2
__global__ __launch_bounds__(256)
void colreduce_kernel(const ushort* __restrict__ h2, float* __restrict__ colsum, int N)
{
    const int c  = threadIdx.x & 127;
    const int rg = threadIdx.x >> 7;
    const int r0 = blockIdx.x * 256;
    const int rEnd = min(r0 + 256, N);
    float acc = 0.0f;
    for (int r = r0 + rg; r < rEnd; r += 2)
        acc += bf2f(h2[(size_t)r * FEAT + c]);
    __shared__ float sh[256];
    sh[threadIdx.x] = acc;
    __syncthreads();
    if (rg == 0) unsafeAtomicAdd(&colsum[c], sh[c] + sh[128 + c]);
}

// ---------------------------------------------------------------- final readout
__global__ __launch_bounds__(128)
void final_kernel(const float* __restrict__ colsum, const float* __restrict__ Wr,
                  const float* __restrict__ br, float* __restrict__ out, float invN)
{
    __shared__ float s0[128], s1[128];
    int j = threadIdx.x;
    float hg = colsum[j] * invN;
    s0[j] = hg * Wr[2 * j + 0];
    s1[j] = hg * Wr[2 * j + 1];
    __syncthreads();
    for (int off = 64; off > 0; off >>= 1) {
        if (j < off) { s0[j] += s0[j + off]; s1[j] += s1[j + off]; }
        __syncthreads();
    }
    if (j == 0) {
        out[0] = s0[0] + br[0];
        out[1] = s1[0] + br[1];
    }
}

// ---------------------------------------------------------------- launch
extern "C" void kernel_launch(void* const* d_in, const int* in_sizes, int n_in,
                              void* d_out, int out_size, void* d_ws, size_t ws_size,
                              hipStream_t stream)
{
    const float* x   = (const float*)d_in[0];
    const int*   src = (const int*)d_in[1];
    const int*   dst = (const int*)d_in[2];
    const float* W1  = (const float*)d_in[3];
    const float* b1  = (const float*)d_in[4];
    const float* W2  = (const float*)d_in[5];
    const float* b2  = (const float*)d_in[6];
    const float* Wr  = (const float*)d_in[7];
    const float* br  = (const float*)d_in[8];
    float* out = (float*)d_out;

    const int N = in_sizes[0] / FEAT;         // 50000
    const int E = in_sizes[1];                // 640000
    const int NP = ((N + 255) / 256) * 256;
    const int NB = (N + 255) / 256;           // <= 256
    const int P  = (N + RSIZE - 1) / RSIZE;   // 13
    const int CS = (E + NCHUNK - 1) / NCHUNK; // 10000

    // workspace layout
    char* p = (char*)d_ws;
    unsigned* partial   = (unsigned*)p;  p += (size_t)2 * P * NCHUNK * RSIZE * 4;
    float*  colsum    = (float*)p;       p += 256 * 4;
    int*    blockSums = (int*)p;         p += 256 * 4;
    int*    cntIn     = (int*)p;         p += (size_t)NP * 4;
    float*  normOut   = (float*)p;       p += (size_t)NP * 4;
    float*  normIn    = (float*)p;       p += (size_t)NP * 4;
    int*    rowStart  = (int*)p;         p += (size_t)(NP + 64) * 4;
    int*    csrSrc    = (int*)p;         p += (size_t)E * 4;
    ushort* bufT      = (ushort*)p;      p += (size_t)N * FEAT * 2;
    ushort* bufH      = (ushort*)p;      p += (size_t)N * FEAT * 2;

    unsigned* partialOut = partial;                                  // job 0 (src)
    unsigned* partialIn  = partial + (size_t)P * NCHUNK * RSIZE;     // job 1 (dst)

    hipMemsetAsync(colsum, 0, 256 * 4, stream);

    // CSR + degree pipeline (no memory-side atomics)
    hist_kernel<<<dim3(NCHUNK, P, 2), 256, 0, stream>>>(src, dst, partial, E, CS);
    merge_kernel<<<NB, 256, 0, stream>>>(partialOut, partialIn, cntIn, normOut, normIn, N);
    scan1_kernel<<<NB, 256, 0, stream>>>(cntIn, blockSums, N);
    rowstart_kernel<<<NB, 256, 0, stream>>>(cntIn, blockSums, rowStart, N, NB, E);
    fill_kernel<<<dim3(NCHUNK, P), 256, 0, stream>>>(src, dst, rowStart, partialIn, csrSrc, N, E, CS);

    const int nStrips = (N + 63) / 64;
    const int gathBlocks = (N + 7) / 8;

    // layer 1 (x fp32 consumed directly, converted inline)
    gemm_mfma_kernel<true><<<256, 256, 0, stream>>>((const void*)x, W1, normOut, bufT, N, nStrips);
    gather_kernel<<<gathBlocks, 256, 0, stream>>>(bufT, rowStart, csrSrc, normIn, b1, bufH, N);

    // layer 2
    gemm_mfma_kernel<false><<<256, 256, 0, stream>>>((const void*)bufH, W2, normOut, bufT, N, nStrips);
    gather_kernel<<<gathBlocks, 256, 0, stream>>>(bufT, rowStart, csrSrc, normIn, b2, bufH, N);

    // readout
    colreduce_kernel<<<NB, 256, 0, stream>>>(bufH, colsum, N);
    final_kernel<<<1, 128, 0, stream>>>(colsum, Wr, br, out, 1.0f / (float)N);
}